// Round 2
// 191.619 us; speedup vs baseline: 1.2004x; 1.2004x over previous
//
#include <hip/hip_runtime.h>
#include <math.h>

#define BB 8
#define HH 512
#define LSEQ 4096
#define NM 64
#define CC 64
#define NCH (LSEQ / CC)
#define L2E 1.44269504088896340736f
#define INV2PI 0.15915494309189535f
#define TWOPI 6.283185307179586f
#define GSTR 136   // GT row stride in shorts: 128 g-cols + 8 pad

typedef __attribute__((ext_vector_type(8))) short short8;
typedef __attribute__((ext_vector_type(4))) float floatx4;

__device__ inline unsigned short f2bf(float x) {
    unsigned int u = __float_as_uint(x);
    unsigned int r = u + 0x7FFFu + ((u >> 16) & 1u);
    return (unsigned short)(r >> 16);
}

// rho^e where rho has log-magnitude m2 (base-2 per unit e) and angle av (revs per unit e)
__device__ inline void cpow(float m2, float av, float e, float& cr, float& ci) {
    float mag = exp2f(m2 * e);
    float rev = av * e; rev -= floorf(rev);
    float s, c;
    __sincosf(rev * TWOPI, &s, &c);
    cr = mag * c; ci = mag * s;
}

// ws layout per (h,n), 8 floats: zr zi Ar Ai wr wi grow ktap
__global__ void dss_setup(const float* __restrict__ W, const float* __restrict__ log_step,
                          const float* __restrict__ Lre, const float* __restrict__ Lim,
                          float* __restrict__ ws) {
    int idx = blockIdx.x * blockDim.x + threadIdx.x;
    if (idx >= HH * NM) return;
    int h = idx >> 6, n = idx & 63;
    float step = expf(log_step[h]);
    float wr = step * Lre[n];
    float wi = step * Lim[n];
    bool grow = wr > 0.0f;
    float mr  = grow ? -wr : wr;
    float phi = grow ? -wi : wi;
    float em = expf(mr);
    float zr = em * cosf(phi);             // rho = e^w (decay) or zeta = e^-w (grow)
    float zi = em * sinf(phi);
    float magL = expf(mr * (float)LSEQ);
    float phiL = phi * (float)LSEQ;
    float rLr = magL * cosf(phiL);
    float rLi = magL * sinf(phiL);
    float dr = 1.0f - zr, di = -zi;
    float den = dr * dr + di * di;
    float sr, si;
    if (den < 1e-24f) { sr = (float)LSEQ; si = 0.0f; }
    else {
        float nr = 1.0f - rLr, ni = -rLi;
        float inv = 1.0f / den;
        sr = (nr * dr + ni * di) * inv;
        si = (ni * dr - nr * di) * inv;
    }
    float s2 = sr * sr + si * si + 1e-7f;
    float is2 = 1.0f / s2;
    float scr =  sr * is2;
    float sci = -si * is2;
    float Wre = W[idx * 2 + 0], Wim = W[idx * 2 + 1];
    float lr = Lre[n], li = Lim[n];
    float il2 = 1.0f / (lr * lr + li * li);
    float qr = (Wre * lr + Wim * li) * il2;
    float qi = (Wim * lr - Wre * li) * il2;
    float Ar = qr * scr - qi * sci;
    float Ai = qr * sci + qi * scr;
    float* o = ws + (size_t)idx * 8;
    o[0] = zr; o[1] = zi; o[2] = Ar; o[3] = Ai;
    o[4] = wr; o[5] = wi; o[6] = grow ? 1.0f : 0.0f; o[7] = 0.0f;
}

// K taps: lane = lag d, loop over modes n (broadcast ws loads, no shuffles).
// K[d] = sum_n Re(A_n z_n^d) (decay) / Re(A_n zeta_n^(L-1-d)) (grow); +D at lag 0
__global__ void dss_khead(const float* __restrict__ D, float* __restrict__ ws) {
    int h = blockIdx.x;
    int d = threadIdx.x;   // 0..63
    float kv = 0.0f;
    #pragma unroll 8
    for (int n = 0; n < NM; ++n) {
        const float* o = ws + (size_t)(h * NM + n) * 8;
        float Ar = o[2], Ai = o[3], wr = o[4], wi = o[5];
        bool grow = wr > 0.0f;
        float e = grow ? (float)(LSEQ - 1 - d) : (float)d;
        float m2 = (grow ? -wr : wr) * L2E;
        float av = (grow ? -wi : wi) * INV2PI;
        float cr, ci;
        cpow(m2, av, e, cr, ci);
        kv += Ar * cr - Ai * ci;
    }
    ws[(size_t)(h * NM + d) * 8 + 7] = kv + ((d == 0) ? D[h] : 0.0f);
}

// One workgroup (4 waves) per (b,h) row. LDS 51456 B -> 3 blocks/CU.
__global__ __launch_bounds__(256, 3) void dss_main(const float* __restrict__ u,
                                                   const float* __restrict__ ws,
                                                   float* __restrict__ y) {
    __shared__ __align__(16) short GT[64 * GSTR];  // [c][k]: staged u bf16 at k 0..63 (phase A),
                                                   // then overwritten by g re/im at k 0..127 (scan)
    __shared__ __align__(16) float ACCY[128 * 66]; // phase A out [m][c] stride 66; later Y [t][c] stride 67
    __shared__ float KTAP[64];

    int tid = threadIdx.x;
    int wv = tid >> 6, lane = tid & 63;
    int mrow = lane & 15;
    int quad = lane >> 4;
    int bh = blockIdx.x;
    int h = bh & (HH - 1);
    const float* ub = u + (size_t)bh * LSEQ;
    float* yb = y + (size_t)bh * LSEQ;

    // ---- stage u -> GT[c][s] as bf16 ----
    #pragma unroll
    for (int i = 0; i < 4; ++i) {
        int q = i * 256 + tid;
        float4 v = ((const float4*)ub)[q];
        int c = q >> 4;
        int s = (q & 15) * 4;
        ushort4 h4;
        h4.x = f2bf(v.x); h4.y = f2bf(v.y); h4.z = f2bf(v.z); h4.w = f2bf(v.w);
        *(ushort4*)&GT[c * GSTR + s] = h4;
    }
    if (tid < 64) KTAP[tid] = ws[(size_t)(h * NM + tid) * 8 + 7];

    // ---- phase-A A-fragments (regs): WA[m=n][s]=Re(cs), WA[64+n][s]=Im(cs)
    // cs = z^(63-s) (decay) / zeta^s (grow); wave wv owns modes 16*wv..16*wv+15
    int nA = 16 * wv + mrow;
    const float* pA = ws + (size_t)(h * NM + nA) * 8;
    float zrA = pA[0], ziA = pA[1], wrA = pA[4], wiA = pA[5];
    bool growA = wrA > 0.0f;
    float m2A = (growA ? -wrA : wrA) * L2E;
    float avA = (growA ? -wiA : wiA) * INV2PI;
    short8 aRe[2], aIm[2];
    #pragma unroll
    for (int ks = 0; ks < 2; ++ks) {
        int s0 = ks * 32 + quad * 8;
        float cr[8], ci[8];
        if (growA) {
            cpow(m2A, avA, (float)s0, cr[0], ci[0]);
            #pragma unroll
            for (int j = 1; j < 8; ++j) {
                cr[j] = cr[j-1]*zrA - ci[j-1]*ziA;
                ci[j] = cr[j-1]*ziA + ci[j-1]*zrA;
            }
        } else {
            cpow(m2A, avA, (float)(56 - s0), cr[7], ci[7]);
            #pragma unroll
            for (int j = 6; j >= 0; --j) {
                cr[j] = cr[j+1]*zrA - ci[j+1]*ziA;
                ci[j] = cr[j+1]*ziA + ci[j+1]*zrA;
            }
        }
        #pragma unroll
        for (int j = 0; j < 8; ++j) {
            aRe[ks][j] = (short)f2bf(cr[j]);
            aIm[ks][j] = (short)f2bf(ci[j]);
        }
    }

    __syncthreads();

    // ---- phase A: ACC[128][64] = WA(128x64) * U(64x64) ----
    // u B-fragments are kept in registers (uf) and reused as phase-C ks=4,5 B-operands.
    floatx4 accR[4], accI[4];
    short8 uf[4][2];
    #pragma unroll
    for (int nt = 0; nt < 4; ++nt) {
        accR[nt] = (floatx4){0.f,0.f,0.f,0.f};
        accI[nt] = (floatx4){0.f,0.f,0.f,0.f};
    }
    #pragma unroll
    for (int nt = 0; nt < 4; ++nt)
        #pragma unroll
        for (int ks = 0; ks < 2; ++ks) {
            uf[nt][ks] = *(const short8*)&GT[(nt*16 + mrow) * GSTR + ks*32 + quad*8];
            accR[nt] = __builtin_amdgcn_mfma_f32_16x16x32_bf16(aRe[ks], uf[nt][ks], accR[nt], 0, 0, 0);
            accI[nt] = __builtin_amdgcn_mfma_f32_16x16x32_bf16(aIm[ks], uf[nt][ks], accI[nt], 0, 0, 0);
        }
    #pragma unroll
    for (int nt = 0; nt < 4; ++nt)
        #pragma unroll
        for (int r = 0; r < 4; ++r) {
            int m = 16*wv + quad*4 + r;
            int col = nt*16 + mrow;
            ACCY[m * 66 + col] = accR[nt][r];
            ACCY[(64 + m) * 66 + col] = accI[nt][r];
        }

    __syncthreads();

    // ---- phase-C A-fragments: WC[t][n]=Re(B), [64+n]=-Im(B), ktap part uses uf regs
    // B = A z^(t+1) (decay) / A zeta^(63-t) (grow); wave wv owns t-tile wv
    int trow = 16 * wv + mrow;
    short8 cf[6];
    #pragma unroll
    for (int g2 = 0; g2 < 2; ++g2)
        #pragma unroll
        for (int j = 0; j < 8; ++j) {
            int n = g2*32 + quad*8 + j;
            const float* pc = ws + (size_t)(h * NM + n) * 8;
            float Ar = pc[2], Ai = pc[3], wr = pc[4], wi = pc[5];
            bool grow = wr > 0.0f;
            float e = grow ? (float)(63 - trow) : (float)(trow + 1);
            float m2 = (grow ? -wr : wr) * L2E;
            float av = (grow ? -wi : wi) * INV2PI;
            float pr_, pi_;
            cpow(m2, av, e, pr_, pi_);
            float Br = Ar*pr_ - Ai*pi_;
            float Bi = Ar*pi_ + Ai*pr_;
            cf[g2][j]   = (short)f2bf(Br);
            cf[2+g2][j] = (short)f2bf(-Bi);
        }
    #pragma unroll
    for (int g2 = 0; g2 < 2; ++g2)
        #pragma unroll
        for (int j = 0; j < 8; ++j) {
            int s = g2*32 + quad*8 + j;
            float v = (s <= trow) ? KTAP[trow - s] : 0.0f;
            cf[4+g2][j] = (short)f2bf(v);
        }

    // ---- scan over 64 chunks (wave 0, lane = mode), fp32 ----
    // Writes g into GT[c][0..127], overwriting staged u (all phase-A u reads done before barrier #2).
    if (wv == 0) {
        int n = lane;
        const float* ps = ws + (size_t)(h * NM + n) * 8;
        float zr = ps[0], zi = ps[1], wr = ps[4], wi = ps[5];
        bool grow = wr > 0.0f;
        float z64r = zr, z64i = zi;         // z^64 by 6 squarings (|z|<=1, underflow safe)
        #pragma unroll
        for (int k = 0; k < 6; ++k) {
            float tr = z64r*z64r - z64i*z64i;
            z64i = 2.0f*z64r*z64i;
            z64r = tr;
        }
        float alr = grow ? 1.0f : z64r, ali = grow ? 0.0f : z64i;
        float tur = grow ? z64r : 1.0f, tui = grow ? z64i : 0.0f;
        float gma = grow ? (-wr * L2E * (float)(LSEQ - CC)) : 0.0f;
        float gmd = grow ? (wr * L2E * (float)CC) : 0.0f;
        float rev0 = grow ? (-wi * INV2PI * (float)(LSEQ - CC)) : 0.0f;
        rev0 -= floorf(rev0);
        float pr_, pi_;
        __sincosf(rev0 * TWOPI, &pi_, &pr_);
        float revs = grow ? (wi * INV2PI * (float)CC) : 0.0f;
        revs -= floorf(revs);
        float spr, spi;
        __sincosf(revs * TWOPI, &spi, &spr);
        float str = 0.0f, sti = 0.0f, btr = 1.0f, bti = 0.0f;
        float ar = ACCY[n * 66 + 0];
        float ai = ACCY[(64 + n) * 66 + 0];
        for (int c = 0; c < NCH; ++c) {
            int cn = (c < NCH-1) ? (c+1) : (NCH-1);
            float nar = ACCY[n * 66 + cn];
            float nai = ACCY[(64 + n) * 66 + cn];
            float gm = exp2f(fmaf(gmd, (float)c, gma));
            float gxr = gm * pr_, gxi = gm * pi_;
            float gr_ = gxr*str - gxi*sti;
            float gi_ = gxr*sti + gxi*str;
            GT[c*GSTR + n]      = (short)f2bf(gr_);
            GT[c*GSTR + 64 + n] = (short)f2bf(gi_);
            float t1r = alr*str - ali*sti + btr*ar - bti*ai;
            float t1i = alr*sti + ali*str + btr*ai + bti*ar;
            str = t1r; sti = t1i;
            float nbr = btr*tur - bti*tui;
            float nbi = btr*tui + bti*tur;
            btr = nbr; bti = nbi;
            float npr = pr_*spr - pi_*spi;
            float npi = pr_*spi + pi_*spr;
            pr_ = npr; pi_ = npi;
            ar = nar; ai = nai;
        }
    }

    __syncthreads();

    // ---- phase C: Y[64 t][64 c] = WC(64x192) * G(192x64); ks 0..3 read g from LDS,
    //      ks 4..5 (ktap * u) reuse the register-held u fragments ----
    floatx4 yacc[4];
    #pragma unroll
    for (int nt = 0; nt < 4; ++nt) yacc[nt] = (floatx4){0.f,0.f,0.f,0.f};
    #pragma unroll
    for (int nt = 0; nt < 4; ++nt) {
        #pragma unroll
        for (int ks = 0; ks < 4; ++ks) {
            short8 bfr = *(const short8*)&GT[(nt*16 + mrow)*GSTR + ks*32 + quad*8];
            yacc[nt] = __builtin_amdgcn_mfma_f32_16x16x32_bf16(cf[ks], bfr, yacc[nt], 0, 0, 0);
        }
        #pragma unroll
        for (int g2 = 0; g2 < 2; ++g2)
            yacc[nt] = __builtin_amdgcn_mfma_f32_16x16x32_bf16(cf[4+g2], uf[nt][g2], yacc[nt], 0, 0, 0);
    }

    // Y to LDS (reuse ACCY, stride 67), then coalesced store
    #pragma unroll
    for (int nt = 0; nt < 4; ++nt)
        #pragma unroll
        for (int r = 0; r < 4; ++r) {
            int t = 16*wv + quad*4 + r;
            int c = nt*16 + mrow;
            ACCY[t * 67 + c] = yacc[nt][r];
        }

    __syncthreads();

    #pragma unroll
    for (int i = 0; i < 4; ++i) {
        int q = i * 256 + tid;
        int l = q * 4;
        int c = l >> 6, t0 = l & 63;
        float4 o;
        o.x = ACCY[(t0+0)*67 + c];
        o.y = ACCY[(t0+1)*67 + c];
        o.z = ACCY[(t0+2)*67 + c];
        o.w = ACCY[(t0+3)*67 + c];
        ((float4*)yb)[q] = o;
    }
}

extern "C" void kernel_launch(void* const* d_in, const int* in_sizes, int n_in,
                              void* d_out, int out_size, void* d_ws, size_t ws_size,
                              hipStream_t stream) {
    const float* u   = (const float*)d_in[0];
    const float* W   = (const float*)d_in[1];
    const float* D   = (const float*)d_in[2];
    const float* ls  = (const float*)d_in[3];
    const float* lre = (const float*)d_in[4];
    const float* lim = (const float*)d_in[5];
    float* y  = (float*)d_out;
    float* ws = (float*)d_ws;   // H*N*8*4 = 1 MiB

    dss_setup<<<(HH * NM + 255) / 256, 256, 0, stream>>>(W, ls, lre, lim, ws);
    dss_khead<<<HH, 64, 0, stream>>>(D, ws);
    dss_main<<<BB * HH, 256, 0, stream>>>(u, ws, y);
}

// Round 5
// 174.464 us; speedup vs baseline: 1.3184x; 1.0983x over previous
//
#include <hip/hip_runtime.h>
#include <math.h>

#define BB 8
#define HH 512
#define LSEQ 4096
#define NM 64
#define CC 64
#define NCH (LSEQ / CC)
#define L2E 1.44269504088896340736f
#define INV2PI 0.15915494309189535f
#define TWOPI 6.283185307179586f
#define GSTR 136   // GT row stride in shorts

typedef __attribute__((ext_vector_type(8))) short short8;
typedef __attribute__((ext_vector_type(4))) float floatx4;

__device__ inline unsigned short f2bf(float x) {
    unsigned int u = __float_as_uint(x);
    unsigned int r = u + 0x7FFFu + ((u >> 16) & 1u);
    return (unsigned short)(r >> 16);
}

// rho^e where rho has log-magnitude m2 (base-2 per unit e) and angle av (revs per unit e)
__device__ inline void cpow(float m2, float av, float e, float& cr, float& ci) {
    float mag = exp2f(m2 * e);
    float rev = av * e; rev -= floorf(rev);
    float s, c;
    __sincosf(rev * TWOPI, &s, &c);
    cr = mag * c; ci = mag * s;
}

// ws layout per (h,n), 8 floats: zr zi Ar Ai wr wi grow ktap
__global__ void dss_setup(const float* __restrict__ W, const float* __restrict__ log_step,
                          const float* __restrict__ Lre, const float* __restrict__ Lim,
                          float* __restrict__ ws) {
    int idx = blockIdx.x * blockDim.x + threadIdx.x;
    if (idx >= HH * NM) return;
    int h = idx >> 6, n = idx & 63;
    float step = expf(log_step[h]);
    float wr = step * Lre[n];
    float wi = step * Lim[n];
    bool grow = wr > 0.0f;
    float mr  = grow ? -wr : wr;
    float phi = grow ? -wi : wi;
    float em = expf(mr);
    float zr = em * cosf(phi);             // rho = e^w (decay) or zeta = e^-w (grow)
    float zi = em * sinf(phi);
    float magL = expf(mr * (float)LSEQ);
    float phiL = phi * (float)LSEQ;
    float rLr = magL * cosf(phiL);
    float rLi = magL * sinf(phiL);
    float dr = 1.0f - zr, di = -zi;
    float den = dr * dr + di * di;
    float sr, si;
    if (den < 1e-24f) { sr = (float)LSEQ; si = 0.0f; }
    else {
        float nr = 1.0f - rLr, ni = -rLi;
        float inv = 1.0f / den;
        sr = (nr * dr + ni * di) * inv;
        si = (ni * dr - nr * di) * inv;
    }
    float s2 = sr * sr + si * si + 1e-7f;
    float is2 = 1.0f / s2;
    float scr =  sr * is2;
    float sci = -si * is2;
    float Wre = W[idx * 2 + 0], Wim = W[idx * 2 + 1];
    float lr = Lre[n], li = Lim[n];
    float il2 = 1.0f / (lr * lr + li * li);
    float qr = (Wre * lr + Wim * li) * il2;
    float qi = (Wim * lr - Wre * li) * il2;
    float Ar = qr * scr - qi * sci;
    float Ai = qr * sci + qi * scr;
    float* o = ws + (size_t)idx * 8;
    o[0] = zr; o[1] = zi; o[2] = Ar; o[3] = Ai;
    o[4] = wr; o[5] = wi; o[6] = grow ? 1.0f : 0.0f; o[7] = 0.0f;
}

// K taps: lane = lag d, loop over modes n (broadcast ws loads, no shuffles).
__global__ void dss_khead(const float* __restrict__ D, float* __restrict__ ws) {
    int h = blockIdx.x;
    int d = threadIdx.x;   // 0..63
    float kv = 0.0f;
    #pragma unroll 8
    for (int n = 0; n < NM; ++n) {
        const float* o = ws + (size_t)(h * NM + n) * 8;
        float Ar = o[2], Ai = o[3], wr = o[4], wi = o[5];
        bool grow = wr > 0.0f;
        float e = grow ? (float)(LSEQ - 1 - d) : (float)d;
        float m2 = (grow ? -wr : wr) * L2E;
        float av = (grow ? -wi : wi) * INV2PI;
        float cr, ci;
        cpow(m2, av, e, cr, ci);
        kv += Ar * cr - Ai * ci;
    }
    ws[(size_t)(h * NM + d) * 8 + 7] = kv + ((d == 0) ? D[h] : 0.0f);
}

// One workgroup (4 waves) per (b,h) row (round-2 structure).
// Scan parallelized across all 4 waves via segmented two-pass (linear recurrence).
__global__ __launch_bounds__(256, 3) void dss_main(const float* __restrict__ u,
                                                   const float* __restrict__ ws,
                                                   float* __restrict__ y) {
    __shared__ __align__(16) short GT[64 * GSTR];  // [c][k]: staged u bf16 at k 0..63 (phase A),
                                                   // then overwritten by g re/im at k 0..127 (scan)
    __shared__ __align__(16) float ACCY[128 * 66]; // phase A out [m][c] stride 66; later Y [t][c] stride 67
    __shared__ float KTAP[64];
    __shared__ float SEGR[3 * 64];                 // per-wave segment sums L_w (re/im), w=0..2
    __shared__ float SEGI[3 * 64];

    int tid = threadIdx.x;
    int wv = tid >> 6, lane = tid & 63;
    int mrow = lane & 15;
    int quad = lane >> 4;
    int bh = blockIdx.x;
    int h = bh & (HH - 1);
    const float* ub = u + (size_t)bh * LSEQ;
    float* yb = y + (size_t)bh * LSEQ;

    // ---- stage u -> GT[c][s] as bf16 ----
    #pragma unroll
    for (int i = 0; i < 4; ++i) {
        int q = i * 256 + tid;
        float4 v = ((const float4*)ub)[q];
        int c = q >> 4;
        int s = (q & 15) * 4;
        ushort4 h4;
        h4.x = f2bf(v.x); h4.y = f2bf(v.y); h4.z = f2bf(v.z); h4.w = f2bf(v.w);
        *(ushort4*)&GT[c * GSTR + s] = h4;
    }
    if (tid < 64) KTAP[tid] = ws[(size_t)(h * NM + tid) * 8 + 7];

    // ---- phase-A A-fragments: WA[m=n][s]=Re(cs), WA[64+n][s]=Im(cs)
    int nA = 16 * wv + mrow;
    const float* pA = ws + (size_t)(h * NM + nA) * 8;
    float zrA = pA[0], ziA = pA[1], wrA = pA[4], wiA = pA[5];
    bool growA = wrA > 0.0f;
    float m2A = (growA ? -wrA : wrA) * L2E;
    float avA = (growA ? -wiA : wiA) * INV2PI;
    short8 aRe[2], aIm[2];
    #pragma unroll
    for (int ks = 0; ks < 2; ++ks) {
        int s0 = ks * 32 + quad * 8;
        float cr[8], ci[8];
        if (growA) {
            cpow(m2A, avA, (float)s0, cr[0], ci[0]);
            #pragma unroll
            for (int j = 1; j < 8; ++j) {
                cr[j] = cr[j-1]*zrA - ci[j-1]*ziA;
                ci[j] = cr[j-1]*ziA + ci[j-1]*zrA;
            }
        } else {
            cpow(m2A, avA, (float)(56 - s0), cr[7], ci[7]);
            #pragma unroll
            for (int j = 6; j >= 0; --j) {
                cr[j] = cr[j+1]*zrA - ci[j+1]*ziA;
                ci[j] = cr[j+1]*ziA + ci[j+1]*zrA;
            }
        }
        #pragma unroll
        for (int j = 0; j < 8; ++j) {
            aRe[ks][j] = (short)f2bf(cr[j]);
            aIm[ks][j] = (short)f2bf(ci[j]);
        }
    }

    // ---- scan constants (per-thread, lane = mode n; used by ALL waves now) ----
    float sc_alr, sc_ali, sc_tur, sc_tui, sc_gma, sc_gmd, sc_p0r, sc_p0i, sc_spr, sc_spi;
    {
        const float* ps = ws + (size_t)(h * NM + lane) * 8;
        float zr = ps[0], zi = ps[1], wr = ps[4], wi = ps[5];
        bool grow = wr > 0.0f;
        float z64r = zr, z64i = zi;         // z^64 by 6 squarings
        #pragma unroll
        for (int k = 0; k < 6; ++k) {
            float tr = z64r*z64r - z64i*z64i;
            z64i = 2.0f*z64r*z64i;
            z64r = tr;
        }
        sc_alr = grow ? 1.0f : z64r; sc_ali = grow ? 0.0f : z64i;
        sc_tur = grow ? z64r : 1.0f; sc_tui = grow ? z64i : 0.0f;
        sc_gma = grow ? (-wr * L2E * (float)(LSEQ - CC)) : 0.0f;
        sc_gmd = grow ? (wr * L2E * (float)CC) : 0.0f;
        float rev0 = grow ? (-wi * INV2PI * (float)(LSEQ - CC)) : 0.0f;
        rev0 -= floorf(rev0);
        __sincosf(rev0 * TWOPI, &sc_p0i, &sc_p0r);
        float revs = grow ? (wi * INV2PI * (float)CC) : 0.0f;
        revs -= floorf(revs);
        __sincosf(revs * TWOPI, &sc_spi, &sc_spr);
    }
    // 16th powers for the segmented scan: M = alpha^16, T = tau^16, Q = sigma^16
    float Mr = sc_alr, Mi = sc_ali, Tr = sc_tur, Ti = sc_tui, Qr = sc_spr, Qi = sc_spi;
    #pragma unroll
    for (int k = 0; k < 4; ++k) {
        float a = Mr*Mr - Mi*Mi; Mi = 2.f*Mr*Mi; Mr = a;
        float b = Tr*Tr - Ti*Ti; Ti = 2.f*Tr*Ti; Tr = b;
        float d = Qr*Qr - Qi*Qi; Qi = 2.f*Qr*Qi; Qr = d;
    }

    __syncthreads();   // B1: u staged, KTAP visible

    // ---- phase A: ACC[128][64] = WA(128x64) * U(64x64) ----
    // u B-fragments kept in registers (uf), reused as phase-C ks=4,5 B-operands.
    floatx4 accR[4], accI[4];
    short8 uf[4][2];
    #pragma unroll
    for (int nt = 0; nt < 4; ++nt) {
        accR[nt] = (floatx4){0.f,0.f,0.f,0.f};
        accI[nt] = (floatx4){0.f,0.f,0.f,0.f};
    }
    #pragma unroll
    for (int nt = 0; nt < 4; ++nt)
        #pragma unroll
        for (int ks = 0; ks < 2; ++ks) {
            uf[nt][ks] = *(const short8*)&GT[(nt*16 + mrow) * GSTR + ks*32 + quad*8];
            accR[nt] = __builtin_amdgcn_mfma_f32_16x16x32_bf16(aRe[ks], uf[nt][ks], accR[nt], 0, 0, 0);
            accI[nt] = __builtin_amdgcn_mfma_f32_16x16x32_bf16(aIm[ks], uf[nt][ks], accI[nt], 0, 0, 0);
        }
    #pragma unroll
    for (int nt = 0; nt < 4; ++nt)
        #pragma unroll
        for (int r = 0; r < 4; ++r) {
            int m = 16*wv + quad*4 + r;
            int col = nt*16 + mrow;
            ACCY[m * 66 + col] = accR[nt][r];
            ACCY[(64 + m) * 66 + col] = accI[nt][r];
        }

    __syncthreads();   // B2

    // ---- scan pass 1 (waves 0..2): local segment sums over chunks [16w, 16w+16) ----
    {
        int n = lane;
        if (wv < 3) {
            float lsr = 0.f, lsi = 0.f, lbr = 1.f, lbi = 0.f;
            #pragma unroll 4
            for (int k = 0; k < 16; ++k) {
                int c = wv * 16 + k;
                float ar = ACCY[n * 66 + c];
                float ai = ACCY[(64 + n) * 66 + c];
                float t1r = sc_alr*lsr - sc_ali*lsi + lbr*ar - lbi*ai;
                float t1i = sc_alr*lsi + sc_ali*lsr + lbr*ai + lbi*ar;
                lsr = t1r; lsi = t1i;
                float nbr = lbr*sc_tur - lbi*sc_tui;
                float nbi = lbr*sc_tui + lbi*sc_tur;
                lbr = nbr; lbi = nbi;
            }
            SEGR[wv * 64 + n] = lsr;
            SEGI[wv * 64 + n] = lsi;
        }
    }

    // ---- phase-C A-fragments (independent of scan; fills time before barrier) ----
    int trow = 16 * wv + mrow;
    short8 cf[6];
    #pragma unroll
    for (int g2 = 0; g2 < 2; ++g2)
        #pragma unroll
        for (int j = 0; j < 8; ++j) {
            int n = g2*32 + quad*8 + j;
            const float* pc = ws + (size_t)(h * NM + n) * 8;
            float Ar = pc[2], Ai = pc[3], wr = pc[4], wi = pc[5];
            bool grow = wr > 0.0f;
            float e = grow ? (float)(63 - trow) : (float)(trow + 1);
            float m2 = (grow ? -wr : wr) * L2E;
            float av = (grow ? -wi : wi) * INV2PI;
            float pr_, pi_;
            cpow(m2, av, e, pr_, pi_);
            float Br = Ar*pr_ - Ai*pi_;
            float Bi = Ar*pi_ + Ai*pr_;
            cf[g2][j]   = (short)f2bf(Br);
            cf[2+g2][j] = (short)f2bf(-Bi);
        }
    #pragma unroll
    for (int g2 = 0; g2 < 2; ++g2)
        #pragma unroll
        for (int j = 0; j < 8; ++j) {
            int s = g2*32 + quad*8 + j;
            float v = (s <= trow) ? KTAP[trow - s] : 0.0f;
            cf[4+g2][j] = (short)f2bf(v);
        }

    __syncthreads();   // B2b: SEG visible

    // ---- scan pass 2 (all waves): prefix from SEG, then original body over own segment ----
    {
        int n = lane;
        float str = 0.f, sti = 0.f, tpr = 1.f, tpi = 0.f, qpr = 1.f, qpi = 0.f;
        #pragma unroll
        for (int v = 0; v < 3; ++v) {
            if (v < wv) {
                float Lr = SEGR[v * 64 + n], Li = SEGI[v * 64 + n];
                float nsr = Mr*str - Mi*sti + tpr*Lr - tpi*Li;
                float nsi = Mr*sti + Mi*str + tpr*Li + tpi*Lr;
                str = nsr; sti = nsi;
                float ntr = tpr*Tr - tpi*Ti, nti = tpr*Ti + tpi*Tr;
                tpr = ntr; tpi = nti;
                float nqr = qpr*Qr - qpi*Qi, nqi = qpr*Qi + qpi*Qr;
                qpr = nqr; qpi = nqi;
            }
        }
        float btr = tpr, bti = tpi;                       // tau^(16w)
        float prr = sc_p0r*qpr - sc_p0i*qpi;              // p0 * sigma^(16w)
        float pri = sc_p0r*qpi + sc_p0i*qpr;
        #pragma unroll 4
        for (int k = 0; k < 16; ++k) {
            int c = wv * 16 + k;
            float ar = ACCY[n * 66 + c];
            float ai = ACCY[(64 + n) * 66 + c];
            float gm = exp2f(fmaf(sc_gmd, (float)c, sc_gma));
            float gxr = gm * prr, gxi = gm * pri;
            float gr_ = gxr * str - gxi * sti;
            float gi_ = gxr * sti + gxi * str;
            GT[c * GSTR + n]      = (short)f2bf(gr_);
            GT[c * GSTR + 64 + n] = (short)f2bf(gi_);
            float t1r = sc_alr*str - sc_ali*sti + btr*ar - bti*ai;
            float t1i = sc_alr*sti + sc_ali*str + btr*ai + bti*ar;
            str = t1r; sti = t1i;
            float nbr = btr*sc_tur - bti*sc_tui;
            float nbi = btr*sc_tui + bti*sc_tur;
            btr = nbr; bti = nbi;
            float npr = prr*sc_spr - pri*sc_spi;
            float npi = prr*sc_spi + pri*sc_spr;
            prr = npr; pri = npi;
        }
    }

    __syncthreads();   // B3: GT(g) complete

    // ---- phase C: Y[64 t][64 c] = WC(64x192) * G(192x64); ks 0..3 read g from LDS,
    //      ks 4..5 (ktap * u) reuse the register-held u fragments ----
    floatx4 yacc[4];
    #pragma unroll
    for (int nt = 0; nt < 4; ++nt) yacc[nt] = (floatx4){0.f,0.f,0.f,0.f};
    #pragma unroll
    for (int nt = 0; nt < 4; ++nt) {
        #pragma unroll
        for (int ks = 0; ks < 4; ++ks) {
            short8 bfr = *(const short8*)&GT[(nt*16 + mrow)*GSTR + ks*32 + quad*8];
            yacc[nt] = __builtin_amdgcn_mfma_f32_16x16x32_bf16(cf[ks], bfr, yacc[nt], 0, 0, 0);
        }
        yacc[nt] = __builtin_amdgcn_mfma_f32_16x16x32_bf16(cf[4], uf[nt][0], yacc[nt], 0, 0, 0);
        yacc[nt] = __builtin_amdgcn_mfma_f32_16x16x32_bf16(cf[5], uf[nt][1], yacc[nt], 0, 0, 0);
    }

    // Y to LDS (reuse ACCY, stride 67), then coalesced store
    #pragma unroll
    for (int nt = 0; nt < 4; ++nt)
        #pragma unroll
        for (int r = 0; r < 4; ++r) {
            int t = 16*wv + quad*4 + r;
            int c = nt*16 + mrow;
            ACCY[t * 67 + c] = yacc[nt][r];
        }

    __syncthreads();   // B4

    #pragma unroll
    for (int i = 0; i < 4; ++i) {
        int q = i * 256 + tid;
        int l = q * 4;
        int c = l >> 6, t0 = l & 63;
        float4 o;
        o.x = ACCY[(t0+0)*67 + c];
        o.y = ACCY[(t0+1)*67 + c];
        o.z = ACCY[(t0+2)*67 + c];
        o.w = ACCY[(t0+3)*67 + c];
        ((float4*)yb)[q] = o;
    }
}

extern "C" void kernel_launch(void* const* d_in, const int* in_sizes, int n_in,
                              void* d_out, int out_size, void* d_ws, size_t ws_size,
                              hipStream_t stream) {
    const float* u   = (const float*)d_in[0];
    const float* W   = (const float*)d_in[1];
    const float* D   = (const float*)d_in[2];
    const float* ls  = (const float*)d_in[3];
    const float* lre = (const float*)d_in[4];
    const float* lim = (const float*)d_in[5];
    float* y  = (float*)d_out;
    float* ws = (float*)d_ws;   // H*N*8*4 = 1 MiB

    dss_setup<<<(HH * NM + 255) / 256, 256, 0, stream>>>(W, ls, lre, lim, ws);
    dss_khead<<<HH, 64, 0, stream>>>(D, ws);
    dss_main<<<BB * HH, 256, 0, stream>>>(u, ws, y);
}